// Round 10
// baseline (931.251 us; speedup 1.0000x reference)
//
#include <hip/hip_runtime.h>
#include <hip/hip_bf16.h>

// ---------------------------------------------------------------------------
// Model2: 5x 4-D conv (+ReLU) -> FC(3840->100)+ReLU -> FC(100->1)+sigmoid
// v10: v9 structure (rolling-window 1-D d1 tiling, shift-packed 32x32x16
// MFMA, B via global_load_lds dbuf). Reg-band-aware T per layer
// (waves/SIMD = floor(512/unified_regs)):
//   conv1 T=3 (104 regs -> 4 waves/SIMD), conv2 T=6 (168 -> 3),
//   conv3 T=3 (108 -> 4, 16 waves/CU vs v9's 8), conv4 T=3, conv5 T=4.
// ---------------------------------------------------------------------------

#define BATCH 256
typedef unsigned int u32;
typedef float    f32x4  __attribute__((ext_vector_type(4)));
typedef float    f32x16 __attribute__((ext_vector_type(16)));
typedef _Float16 f16x8  __attribute__((ext_vector_type(8)));

struct __attribute__((packed, aligned(4))) f16x8w { f16x8 v; };  // 4B-aligned 16B load

// --------------------------- fp32 -> f16 convert ---------------------------
__global__ void cvt_f32_f16(const float* __restrict__ in, _Float16* __restrict__ o, int n8) {
    int i = blockIdx.x * blockDim.x + threadIdx.x;
    if (i >= n8) return;
    const f32x4* p = (const f32x4*)(in + (size_t)i * 8);
    f32x4 a = p[0], b = p[1];
    f16x8 v;
    #pragma unroll
    for (int j = 0; j < 4; ++j) { v[j] = (_Float16)a[j]; v[4 + j] = (_Float16)b[j]; }
    *(f16x8*)(o + (size_t)i * 8) = v;
}

// --------------------------- weight prepack (v5 order) ---------------------
// st = ((ci*KS + k2)*2 + k3p)*KS + k1.  Within a step: k_local = g*8 + j,
// k3 = k3p*2 + g, k4' = j.  col = lane&31 = oc*S + s.
template<int COUT, int CIN, int KS, int S>
__global__ void prepack_v5(const float* __restrict__ w, _Float16* __restrict__ wf) {
    constexpr int STEPS = CIN * KS * 2 * KS;
    constexpr int TOT = STEPS * 512;
    int idx = blockIdx.x * 256 + threadIdx.x;
    if (idx >= TOT) return;
    int j    = idx & 7;
    int lane = (idx >> 3) & 63;
    int st   = idx >> 9;
    int k1 = st % KS;
    int r1 = st / KS;
    int k3p = r1 & 1;
    int r2  = r1 >> 1;
    int k2 = r2 % KS;
    int ci = r2 / KS;
    int gg = lane >> 5, col = lane & 31;
    int oc = col / S, s = col % S;
    int k3 = k3p * 2 + gg;
    int k4 = j - s;
    float v = 0.0f;
    if (oc < COUT && k3 < KS && k4 >= 0 && k4 < KS)
        v = w[((((oc * CIN + ci) * KS + k1) * KS + k2) * KS + k3) * KS + k4];
    wf[idx] = (_Float16)v;
}

// --------------------------- LDS staging helper ----------------------------
template<int BYTES>
__device__ __forceinline__ void stage_b(const _Float16* gsrc, char* ldst, int tid) {
    constexpr int N16 = BYTES / 16;
    const int wv = tid >> 6, ln = tid & 63;
    #pragma unroll
    for (int it = 0; it * 256 < N16; ++it) {
        int u16 = it * 256 + (wv << 6);            // wave-uniform 16B-unit index
        if (u16 < N16) {
            const char* gp = (const char*)gsrc + (size_t)(u16 + ln) * 16;
            __builtin_amdgcn_global_load_lds(
                (const __attribute__((address_space(1))) unsigned int*)gp,
                (__attribute__((address_space(3))) unsigned int*)(ldst + u16 * 16),
                16, 0, 0);
        }
    }
}

// --------------------------- conv kernel (v10) -----------------------------
template<int CIN, int COUT, int KS, int DIN, int DP, int S, int OP, int T,
         int CG, int MINW>
__launch_bounds__(256, MINW)
__global__ void conv4d_v10(const _Float16* __restrict__ x,
                           const _Float16* __restrict__ wf,
                           const float* __restrict__ bias,
                           _Float16* __restrict__ out) {
    constexpr int DOUT = DIN - KS + 1;
    constexpr int NB   = (DOUT + S - 1) / S;
    constexpr int PCOL = DOUT * DOUT * NB;         // (d2,d3,u) rows per (b,d1)
    constexpr int NTC  = (PCOL + 31) / 32;
    constexpr int NG   = DOUT / T;                 // d1 groups
    static_assert(DOUT % T == 0, "T must divide DOUT");
    constexpr int XD2 = DIN * DP;
    constexpr int XD1 = DIN * XD2;
    constexpr int XCI = DIN * XD1;
    constexpr int GROUPS = CIN * KS * 2;
    static_assert(GROUPS % CG == 0, "CG must divide GROUPS");
    constexpr int CSTEPS = CG * KS;
    constexpr int CBYTES = CSTEPS * 1024;
    constexpr int NCHUNK = GROUPS / CG;
    constexpr int NBUF   = (NCHUNK > 1) ? 2 : 1;
    constexpr int AJ = T + KS - 1;                 // rows touched per group
    constexpr int W  = T + 1;                      // rolling window slots
    constexpr u32 NW   = (u32)BATCH * NG * NTC;
    constexpr u32 POUT = (u32)DOUT * DOUT * DOUT * OP;

    __shared__ char bsm[NBUF * CBYTES];
    const int tid = threadIdx.x;
    u32 wid = blockIdx.x * 4u + (u32)(tid >> 6);
    if (wid >= NW) wid = NW - 1u;
    const int ln = tid & 63;
    const int g  = ln >> 5;
    const int r  = ln & 31;

    u32 tc = wid % (u32)NTC;  u32 q = wid / (u32)NTC;
    u32 d1g = q % (u32)NG;    u32 b = q / (u32)NG;
    u32 rr = tc * 32u + (u32)r;  if (rr >= (u32)PCOL) rr = (u32)PCOL - 1u;
    u32 u  = rr % (u32)NB;    u32 q2 = rr / (u32)NB;
    u32 d3 = q2 % (u32)DOUT;  u32 d2 = q2 / (u32)DOUT;

    const u32 lanebase2 = (b * (u32)(CIN * XCI) + d1g * (u32)(T * XD1)
                         + d2 * (u32)XD2 + d3 * (u32)DP + (u32)(g * DP)
                         + u * (u32)S) * 2u;
    const char* xc = (const char*)x;

    f32x16 acc[T];
    #pragma unroll
    for (int t = 0; t < T; ++t)
        #pragma unroll
        for (int i = 0; i < 16; ++i) acc[t][i] = 0.0f;

    stage_b<CBYTES>(wf, &bsm[0], tid);

    #pragma unroll 1
    for (int ch = 0; ch < NCHUNK; ++ch) {
        __syncthreads();   // staging for chunk ch complete (vmcnt drained)
        if (NCHUNK > 1 && ch + 1 < NCHUNK)
            stage_b<CBYTES>(wf + (size_t)(ch + 1) * CSTEPS * 512,
                            &bsm[((ch + 1) & 1) * CBYTES], tid);
        const char* bb = &bsm[(ch & 1) * (NBUF > 1 ? CBYTES : 0)] + ln * 16;
        #pragma unroll
        for (int gi = 0; gi < CG; ++gi) {
            int grp = ch * CG + gi;
            int k3p = grp & 1;
            int k2  = (grp >> 1) % KS;
            int ci  = (grp >> 1) / KS;
            u32 goff = ((u32)ci * (u32)XCI + (u32)k2 * (u32)XD2
                      + (u32)(k3p * 2 * DP)) * 2u;
            const char* ap = xc + lanebase2 + goff;

            // Rolling (T+1)-slot window; all indices compile-time constants.
            f16x8 ar[W];
            #pragma unroll
            for (int j = 0; j < T; ++j)
                ar[j] = ((const f16x8w*)(ap + j * (XD1 * 2)))->v;
            #pragma unroll
            for (int k1 = 0; k1 < KS; ++k1) {
                if (T + k1 < AJ)
                    ar[(T + k1) % W] = ((const f16x8w*)(ap + (T + k1) * (XD1 * 2)))->v;
                f16x8 bf = *(const f16x8*)(bb + (gi * KS + k1) * 1024);
                #pragma unroll
                for (int t = 0; t < T; ++t)
                    acc[t] = __builtin_amdgcn_mfma_f32_32x32x16_f16(
                        ar[(k1 + t) % W], bf, acc[t], 0, 0, 0);
            }
        }
    }

    // Epilogue. D: col = lane&31 = oc*S+s, row = (reg&3) + 8*(reg>>2) + 4*g.
    const int oc = r / S, s = r % S;
    if (oc >= COUT) return;
    float bv = bias[oc];
    #pragma unroll
    for (int reg = 0; reg < 16; ++reg) {
        int rowoff = (reg & 3) + 8 * (reg >> 2) + 4 * g;
        u32 rr2 = tc * 32u + (u32)rowoff;
        if (rr2 >= (u32)PCOL) rr2 = (u32)PCOL - 1u;
        u32 uu = rr2 % (u32)NB;  u32 qq = rr2 / (u32)NB;
        u32 dd3 = qq % (u32)DOUT; u32 dd2 = qq / (u32)DOUT;
        u32 d4 = uu * (u32)S + (u32)s;
        if (d4 < (u32)DOUT) {
            u32 obase = (b * (u32)COUT + (u32)oc) * POUT
                      + (dd2 * (u32)DOUT + dd3) * (u32)OP + d4
                      + d1g * (u32)(T * DOUT * DOUT * OP);
            #pragma unroll
            for (int t = 0; t < T; ++t)
                out[obase + (u32)t * (u32)(DOUT * DOUT * OP)]
                    = (_Float16)fmaxf(acc[t][reg] + bv, 0.0f);
        }
    }
}

// --------------------------- FC1 (MFMA 16x16x32) ---------------------------
__global__ void prepack_fc1(const float* __restrict__ w, _Float16* __restrict__ wf) {
    int idx = blockIdx.x * 256 + threadIdx.x;        // 7*120*64*8 = 430080
    if (idx >= 430080) return;
    int j    = idx & 7;
    int lane = (idx >> 3) & 63;
    int t9   = idx >> 9;
    int st   = t9 % 120;
    int ni   = t9 / 120;
    int k    = st * 32 + (lane >> 4) * 8 + j;
    int col  = ni * 16 + (lane & 15);
    wf[idx] = (_Float16)((col < 100) ? w[k * 100 + col] : 0.0f);
}

__launch_bounds__(256)
__global__ void fc1_mfma(const _Float16* __restrict__ h,
                         const _Float16* __restrict__ wfc,
                         const float* __restrict__ bias,
                         float* __restrict__ o) {
    int wv   = blockIdx.x * 4 + (threadIdx.x >> 6);   // 0..111
    int lane = threadIdx.x & 63;
    int r = lane & 15, g = lane >> 4;
    int mi = wv / 7, ni = wv % 7;
    const f16x8* A  = (const f16x8*)(h + (size_t)(mi * 16 + r) * 3840);
    const f16x8* Bv = (const f16x8*)wfc;
    f32x4 acc = {0.f, 0.f, 0.f, 0.f};
    #pragma unroll 4
    for (int st = 0; st < 120; ++st) {
        f16x8 a = A[st * 4 + g];
        f16x8 b = Bv[(ni * 120 + st) * 64 + lane];
        acc = __builtin_amdgcn_mfma_f32_16x16x32_f16(a, b, acc, 0, 0, 0);
    }
    int col = ni * 16 + r;
    if (col < 100) {
        float bv = bias[col];
        #pragma unroll
        for (int i = 0; i < 4; ++i) {
            int row = mi * 16 + g * 4 + i;
            o[row * 100 + col] = fmaxf(acc[i] + bv, 0.0f);
        }
    }
}

// --------------------------- FC2 + sigmoid ---------------------------------
__global__ void fc2_sigmoid(const float* __restrict__ h,
                            const float* __restrict__ w,
                            const float* __restrict__ bias,
                            float* __restrict__ out) {
    int b = blockIdx.x * blockDim.x + threadIdx.x;
    if (b >= BATCH) return;
    const float* hb = h + b * 100;
    float acc = bias[0];
    #pragma unroll
    for (int j = 0; j < 100; ++j)
        acc = fmaf(hb[j], w[j], acc);
    out[b] = 1.0f / (1.0f + expf(-acc));
}

// --------------------------- launch ----------------------------------------
extern "C" void kernel_launch(void* const* d_in, const int* in_sizes, int n_in,
                              void* d_out, int out_size, void* d_ws, size_t ws_size,
                              hipStream_t stream) {
    const float* x    = (const float*)d_in[0];
    const float* w1   = (const float*)d_in[1];
    const float* b1   = (const float*)d_in[2];
    const float* w2   = (const float*)d_in[3];
    const float* b2   = (const float*)d_in[4];
    const float* w3   = (const float*)d_in[5];
    const float* b3   = (const float*)d_in[6];
    const float* w4   = (const float*)d_in[7];
    const float* b4   = (const float*)d_in[8];
    const float* w5   = (const float*)d_in[9];
    const float* b5   = (const float*)d_in[10];
    const float* fc1w = (const float*)d_in[11];
    const float* fc1b = (const float*)d_in[12];
    const float* fc2w = (const float*)d_in[13];
    const float* fc2b = (const float*)d_in[14];
    float* out = (float*)d_out;

    _Float16* W = (_Float16*)d_ws;
    size_t cur = 0;
    auto alloc = [&](size_t n) { _Float16* p = W + cur; cur += (n + 255) & ~(size_t)255; return p; };
    _Float16* x16 = alloc(26873856);            // [256,1,18,18,18,18]
    _Float16* h1  = alloc(41472000);            // [256,3,15,15,15,(16)]
    _Float16* h2  = alloc(47775744);            // [256,9,12,12,12,12]
    _Float16* h3  = alloc(22394880);            // [256,12,9,9,9,(10)]
    _Float16* h4  = alloc(4976640);             // [256,15,6,6,6,6]
    _Float16* h5  = alloc(983040);              // [256,3840] flatten-exact
    _Float16* wf1 = alloc(16384);               // 32 steps * 512
    _Float16* wf2 = alloc(49152);               // 96
    _Float16* wf3 = alloc(147456);              // 288
    _Float16* wf4 = alloc(196608);              // 384
    _Float16* wf5 = alloc(138240);              // 270
    _Float16* wfc = alloc(430080);
    float* fc1out = (float*)alloc(51200 + 256); // [256,100] f32

    cvt_f32_f16<<<13122, 256, 0, stream>>>(x, x16, 3359232);

    prepack_v5<3, 1, 4, 4><<<64,  256, 0, stream>>>(w1, wf1);
    prepack_v5<9, 3, 4, 2><<<192, 256, 0, stream>>>(w2, wf2);
    prepack_v5<12, 9, 4, 2><<<576, 256, 0, stream>>>(w3, wf3);
    prepack_v5<15, 12, 4, 2><<<768, 256, 0, stream>>>(w4, wf4);
    prepack_v5<15, 15, 3, 2><<<540, 256, 0, stream>>>(w5, wf5);
    prepack_fc1<<<1680, 256, 0, stream>>>(fc1w, wfc);

    // convs: <CIN,COUT,KS,DIN,DP,S,OP,T,CG,MINW>, grid = ceil(NW/4)
    // conv1: T=3 -> NG=5, NTC=29, NW=37120; CG=8 single chunk (32KB, no dbuf)
    //   regs ~ 48 acc + 16 win + 40 = 104 -> 4 waves/SIMD
    conv4d_v10<1, 3, 4, 18, 18, 4, 16, 3, 8, 4><<<9280, 256, 0, stream>>>(x16, wf1, b1, h1);
    // conv2: T=6 -> NG=2, NTC=27, NW=13824; CG=4 (dbuf 32KB)
    //   regs ~ 96 + 28 + 44 = 168 -> 3 waves/SIMD
    conv4d_v10<3, 9, 4, 15, 16, 2, 12, 6, 4, 3><<<3456, 256, 0, stream>>>(h1, wf2, b2, h2);
    // conv3: T=3 -> NG=3, NTC=13, NW=9984; CG=4 (dbuf 32KB)
    //   regs ~ 48 + 16 + 44 = 108 -> 4 waves/SIMD, 16 waves/CU
    conv4d_v10<9, 12, 4, 12, 12, 2, 10, 3, 4, 4><<<2496, 256, 0, stream>>>(h2, wf3, b3, h3);
    // conv4: T=3 -> NG=2, NTC=4, NW=2048; regs ~108 -> 4 waves/SIMD
    conv4d_v10<12, 15, 4, 9, 10, 2, 6, 3, 4, 4><<<512, 256, 0, stream>>>(h3, wf4, b4, h4);
    // conv5: T=4, CG=6, NW=256; regs ~124 -> 4 waves/SIMD
    conv4d_v10<15, 15, 3, 6, 6, 2, 4, 4, 6, 4><<<64, 256, 0, stream>>>(h4, wf5, b5, h5);

    fc1_mfma<<<28, 256, 0, stream>>>(h5, wfc, fc1b, fc1out);
    fc2_sigmoid<<<1, 256, 0, stream>>>(fc1out, fc2w, fc2b, out);
}

// Round 11
// 912.541 us; speedup vs baseline: 1.0205x; 1.0205x over previous
//
#include <hip/hip_runtime.h>
#include <hip/hip_bf16.h>

// ---------------------------------------------------------------------------
// Model2: 5x 4-D conv (+ReLU) -> FC(3840->100)+ReLU -> FC(100->1)+sigmoid
// v11: v10 structure (1-D d1 tiling, shift-packed 32x32x16 MFMA, B via
// global_load_lds dbuf) with GROUP-LEVEL A DOUBLE-BUFFERING: at group g the
// wave issues all AJ loads of group g+1 into ar[(g+1)&1], then runs group
// g's KS*T MFMAs from ar[g&1] -> load latency (~500cy) hidden under a full
// MFMA burst (512-768 SIMD-cy) instead of ~1 k1-step (v10's rolling window).
// ---------------------------------------------------------------------------

#define BATCH 256
typedef unsigned int u32;
typedef float    f32x4  __attribute__((ext_vector_type(4)));
typedef float    f32x16 __attribute__((ext_vector_type(16)));
typedef _Float16 f16x8  __attribute__((ext_vector_type(8)));

struct __attribute__((packed, aligned(4))) f16x8w { f16x8 v; };  // 4B-aligned 16B load

// --------------------------- fp32 -> f16 convert ---------------------------
__global__ void cvt_f32_f16(const float* __restrict__ in, _Float16* __restrict__ o, int n8) {
    int i = blockIdx.x * blockDim.x + threadIdx.x;
    if (i >= n8) return;
    const f32x4* p = (const f32x4*)(in + (size_t)i * 8);
    f32x4 a = p[0], b = p[1];
    f16x8 v;
    #pragma unroll
    for (int j = 0; j < 4; ++j) { v[j] = (_Float16)a[j]; v[4 + j] = (_Float16)b[j]; }
    *(f16x8*)(o + (size_t)i * 8) = v;
}

// --------------------------- weight prepack (v5 order) ---------------------
// st = ((ci*KS + k2)*2 + k3p)*KS + k1.  Within a step: k_local = g*8 + j,
// k3 = k3p*2 + g, k4' = j.  col = lane&31 = oc*S + s.
template<int COUT, int CIN, int KS, int S>
__global__ void prepack_v5(const float* __restrict__ w, _Float16* __restrict__ wf) {
    constexpr int STEPS = CIN * KS * 2 * KS;
    constexpr int TOT = STEPS * 512;
    int idx = blockIdx.x * 256 + threadIdx.x;
    if (idx >= TOT) return;
    int j    = idx & 7;
    int lane = (idx >> 3) & 63;
    int st   = idx >> 9;
    int k1 = st % KS;
    int r1 = st / KS;
    int k3p = r1 & 1;
    int r2  = r1 >> 1;
    int k2 = r2 % KS;
    int ci = r2 / KS;
    int gg = lane >> 5, col = lane & 31;
    int oc = col / S, s = col % S;
    int k3 = k3p * 2 + gg;
    int k4 = j - s;
    float v = 0.0f;
    if (oc < COUT && k3 < KS && k4 >= 0 && k4 < KS)
        v = w[((((oc * CIN + ci) * KS + k1) * KS + k2) * KS + k3) * KS + k4];
    wf[idx] = (_Float16)v;
}

// --------------------------- LDS staging helper ----------------------------
template<int BYTES>
__device__ __forceinline__ void stage_b(const _Float16* gsrc, char* ldst, int tid) {
    constexpr int N16 = BYTES / 16;
    const int wv = tid >> 6, ln = tid & 63;
    #pragma unroll
    for (int it = 0; it * 256 < N16; ++it) {
        int u16 = it * 256 + (wv << 6);            // wave-uniform 16B-unit index
        if (u16 < N16) {
            const char* gp = (const char*)gsrc + (size_t)(u16 + ln) * 16;
            __builtin_amdgcn_global_load_lds(
                (const __attribute__((address_space(1))) unsigned int*)gp,
                (__attribute__((address_space(3))) unsigned int*)(ldst + u16 * 16),
                16, 0, 0);
        }
    }
}

// --------------------------- conv kernel (v11) -----------------------------
template<int CIN, int COUT, int KS, int DIN, int DP, int S, int OP, int T,
         int CG, int MINW>
__launch_bounds__(256, MINW)
__global__ void conv4d_v11(const _Float16* __restrict__ x,
                           const _Float16* __restrict__ wf,
                           const float* __restrict__ bias,
                           _Float16* __restrict__ out) {
    constexpr int DOUT = DIN - KS + 1;
    constexpr int NB   = (DOUT + S - 1) / S;
    constexpr int PCOL = DOUT * DOUT * NB;         // (d2,d3,u) rows per (b,d1)
    constexpr int NTC  = (PCOL + 31) / 32;
    constexpr int NG   = DOUT / T;                 // d1 groups
    static_assert(DOUT % T == 0, "T must divide DOUT");
    constexpr int XD2 = DIN * DP;
    constexpr int XD1 = DIN * XD2;
    constexpr int XCI = DIN * XD1;
    constexpr int GROUPS = CIN * KS * 2;
    static_assert(GROUPS % CG == 0, "CG must divide GROUPS");
    static_assert(CG % 2 == 0, "CG even so buffer parity gi&1 is consistent");
    constexpr int CSTEPS = CG * KS;
    constexpr int CBYTES = CSTEPS * 1024;
    constexpr int NCHUNK = GROUPS / CG;
    constexpr int NBUF   = (NCHUNK > 1) ? 2 : 1;
    constexpr int AJ = T + KS - 1;                 // rows per group window
    constexpr u32 NW   = (u32)BATCH * NG * NTC;
    constexpr u32 POUT = (u32)DOUT * DOUT * DOUT * OP;

    __shared__ char bsm[NBUF * CBYTES];
    const int tid = threadIdx.x;
    u32 wid = blockIdx.x * 4u + (u32)(tid >> 6);
    if (wid >= NW) wid = NW - 1u;
    const int ln = tid & 63;
    const int g  = ln >> 5;
    const int r  = ln & 31;

    u32 tc = wid % (u32)NTC;  u32 q = wid / (u32)NTC;
    u32 d1g = q % (u32)NG;    u32 b = q / (u32)NG;
    u32 rr = tc * 32u + (u32)r;  if (rr >= (u32)PCOL) rr = (u32)PCOL - 1u;
    u32 u  = rr % (u32)NB;    u32 q2 = rr / (u32)NB;
    u32 d3 = q2 % (u32)DOUT;  u32 d2 = q2 / (u32)DOUT;

    const u32 lanebase2 = (b * (u32)(CIN * XCI) + d1g * (u32)(T * XD1)
                         + d2 * (u32)XD2 + d3 * (u32)DP + (u32)(g * DP)
                         + u * (u32)S) * 2u;
    const char* xc = (const char*)x;

    f32x16 acc[T];
    #pragma unroll
    for (int t = 0; t < T; ++t)
        #pragma unroll
        for (int i = 0; i < 16; ++i) acc[t][i] = 0.0f;

    stage_b<CBYTES>(wf, &bsm[0], tid);

    // Double-buffered A-window; parity gi&1 is compile-time (gi fully unrolled).
    f16x8 ar[2][AJ];
    {   // preload group 0 (ci=0, k2=0, k3p=0 -> offset 0)
        const char* ap0 = xc + lanebase2;
        #pragma unroll
        for (int j = 0; j < AJ; ++j)
            ar[0][j] = ((const f16x8w*)(ap0 + j * (XD1 * 2)))->v;
    }

    #pragma unroll 1
    for (int ch = 0; ch < NCHUNK; ++ch) {
        __syncthreads();   // staging for chunk ch complete (vmcnt drained)
        if (NCHUNK > 1 && ch + 1 < NCHUNK)
            stage_b<CBYTES>(wf + (size_t)(ch + 1) * CSTEPS * 512,
                            &bsm[((ch + 1) & 1) * CBYTES], tid);
        const char* bb = &bsm[(ch & 1) * (NBUF > 1 ? CBYTES : 0)] + ln * 16;
        #pragma unroll
        for (int gi = 0; gi < CG; ++gi) {
            const int grp = ch * CG + gi;
            // 1) issue next group's full window into the spare buffer
            if (grp + 1 < GROUPS) {
                int g2  = grp + 1;
                int k3p = g2 & 1;
                int k2  = (g2 >> 1) % KS;
                int ci  = (g2 >> 1) / KS;
                u32 goff = ((u32)ci * (u32)XCI + (u32)k2 * (u32)XD2
                          + (u32)(k3p * 2 * DP)) * 2u;
                const char* ap = xc + lanebase2 + goff;
                #pragma unroll
                for (int j = 0; j < AJ; ++j)
                    ar[(gi + 1) & 1][j] = ((const f16x8w*)(ap + j * (XD1 * 2)))->v;
            }
            // 2) MFMAs for current group from the full buffer
            #pragma unroll
            for (int k1 = 0; k1 < KS; ++k1) {
                f16x8 bf = *(const f16x8*)(bb + (gi * KS + k1) * 1024);
                #pragma unroll
                for (int t = 0; t < T; ++t)
                    acc[t] = __builtin_amdgcn_mfma_f32_32x32x16_f16(
                        ar[gi & 1][k1 + t], bf, acc[t], 0, 0, 0);
            }
        }
    }

    // Epilogue. D: col = lane&31 = oc*S+s, row = (reg&3) + 8*(reg>>2) + 4*g.
    const int oc = r / S, s = r % S;
    if (oc >= COUT) return;
    float bv = bias[oc];
    #pragma unroll
    for (int reg = 0; reg < 16; ++reg) {
        int rowoff = (reg & 3) + 8 * (reg >> 2) + 4 * g;
        u32 rr2 = tc * 32u + (u32)rowoff;
        if (rr2 >= (u32)PCOL) rr2 = (u32)PCOL - 1u;
        u32 uu = rr2 % (u32)NB;  u32 qq = rr2 / (u32)NB;
        u32 dd3 = qq % (u32)DOUT; u32 dd2 = qq / (u32)DOUT;
        u32 d4 = uu * (u32)S + (u32)s;
        if (d4 < (u32)DOUT) {
            u32 obase = (b * (u32)COUT + (u32)oc) * POUT
                      + (dd2 * (u32)DOUT + dd3) * (u32)OP + d4
                      + d1g * (u32)(T * DOUT * DOUT * OP);
            #pragma unroll
            for (int t = 0; t < T; ++t)
                out[obase + (u32)t * (u32)(DOUT * DOUT * OP)]
                    = (_Float16)fmaxf(acc[t][reg] + bv, 0.0f);
        }
    }
}

// --------------------------- FC1 (MFMA 16x16x32) ---------------------------
__global__ void prepack_fc1(const float* __restrict__ w, _Float16* __restrict__ wf) {
    int idx = blockIdx.x * 256 + threadIdx.x;        // 7*120*64*8 = 430080
    if (idx >= 430080) return;
    int j    = idx & 7;
    int lane = (idx >> 3) & 63;
    int t9   = idx >> 9;
    int st   = t9 % 120;
    int ni   = t9 / 120;
    int k    = st * 32 + (lane >> 4) * 8 + j;
    int col  = ni * 16 + (lane & 15);
    wf[idx] = (_Float16)((col < 100) ? w[k * 100 + col] : 0.0f);
}

__launch_bounds__(256)
__global__ void fc1_mfma(const _Float16* __restrict__ h,
                         const _Float16* __restrict__ wfc,
                         const float* __restrict__ bias,
                         float* __restrict__ o) {
    int wv   = blockIdx.x * 4 + (threadIdx.x >> 6);   // 0..111
    int lane = threadIdx.x & 63;
    int r = lane & 15, g = lane >> 4;
    int mi = wv / 7, ni = wv % 7;
    const f16x8* A  = (const f16x8*)(h + (size_t)(mi * 16 + r) * 3840);
    const f16x8* Bv = (const f16x8*)wfc;
    f32x4 acc = {0.f, 0.f, 0.f, 0.f};
    #pragma unroll 4
    for (int st = 0; st < 120; ++st) {
        f16x8 a = A[st * 4 + g];
        f16x8 b = Bv[(ni * 120 + st) * 64 + lane];
        acc = __builtin_amdgcn_mfma_f32_16x16x32_f16(a, b, acc, 0, 0, 0);
    }
    int col = ni * 16 + r;
    if (col < 100) {
        float bv = bias[col];
        #pragma unroll
        for (int i = 0; i < 4; ++i) {
            int row = mi * 16 + g * 4 + i;
            o[row * 100 + col] = fmaxf(acc[i] + bv, 0.0f);
        }
    }
}

// --------------------------- FC2 + sigmoid ---------------------------------
__global__ void fc2_sigmoid(const float* __restrict__ h,
                            const float* __restrict__ w,
                            const float* __restrict__ bias,
                            float* __restrict__ out) {
    int b = blockIdx.x * blockDim.x + threadIdx.x;
    if (b >= BATCH) return;
    const float* hb = h + b * 100;
    float acc = bias[0];
    #pragma unroll
    for (int j = 0; j < 100; ++j)
        acc = fmaf(hb[j], w[j], acc);
    out[b] = 1.0f / (1.0f + expf(-acc));
}

// --------------------------- launch ----------------------------------------
extern "C" void kernel_launch(void* const* d_in, const int* in_sizes, int n_in,
                              void* d_out, int out_size, void* d_ws, size_t ws_size,
                              hipStream_t stream) {
    const float* x    = (const float*)d_in[0];
    const float* w1   = (const float*)d_in[1];
    const float* b1   = (const float*)d_in[2];
    const float* w2   = (const float*)d_in[3];
    const float* b2   = (const float*)d_in[4];
    const float* w3   = (const float*)d_in[5];
    const float* b3   = (const float*)d_in[6];
    const float* w4   = (const float*)d_in[7];
    const float* b4   = (const float*)d_in[8];
    const float* w5   = (const float*)d_in[9];
    const float* b5   = (const float*)d_in[10];
    const float* fc1w = (const float*)d_in[11];
    const float* fc1b = (const float*)d_in[12];
    const float* fc2w = (const float*)d_in[13];
    const float* fc2b = (const float*)d_in[14];
    float* out = (float*)d_out;

    _Float16* W = (_Float16*)d_ws;
    size_t cur = 0;
    auto alloc = [&](size_t n) { _Float16* p = W + cur; cur += (n + 255) & ~(size_t)255; return p; };
    _Float16* x16 = alloc(26873856);            // [256,1,18,18,18,18]
    _Float16* h1  = alloc(41472000);            // [256,3,15,15,15,(16)]
    _Float16* h2  = alloc(47775744);            // [256,9,12,12,12,12]
    _Float16* h3  = alloc(22394880);            // [256,12,9,9,9,(10)]
    _Float16* h4  = alloc(4976640);             // [256,15,6,6,6,6]
    _Float16* h5  = alloc(983040);              // [256,3840] flatten-exact
    _Float16* wf1 = alloc(16384);               // 32 steps * 512
    _Float16* wf2 = alloc(49152);               // 96
    _Float16* wf3 = alloc(147456);              // 288
    _Float16* wf4 = alloc(196608);              // 384
    _Float16* wf5 = alloc(138240);              // 270
    _Float16* wfc = alloc(430080);
    float* fc1out = (float*)alloc(51200 + 256); // [256,100] f32

    cvt_f32_f16<<<13122, 256, 0, stream>>>(x, x16, 3359232);

    prepack_v5<3, 1, 4, 4><<<64,  256, 0, stream>>>(w1, wf1);
    prepack_v5<9, 3, 4, 2><<<192, 256, 0, stream>>>(w2, wf2);
    prepack_v5<12, 9, 4, 2><<<576, 256, 0, stream>>>(w3, wf3);
    prepack_v5<15, 12, 4, 2><<<768, 256, 0, stream>>>(w4, wf4);
    prepack_v5<15, 15, 3, 2><<<540, 256, 0, stream>>>(w5, wf5);
    prepack_fc1<<<1680, 256, 0, stream>>>(fc1w, wfc);

    // convs: <CIN,COUT,KS,DIN,DP,S,OP,T,CG,MINW>, grid = ceil(NW/4)
    // conv1: T=3, CG=8 -> single 32KB chunk, no in-loop barriers; NW=37120
    //   regs ~ 48 acc + 48 dbuf + 45 = 141 -> 3 waves/SIMD
    conv4d_v11<1, 3, 4, 18, 18, 4, 16, 3, 8, 3><<<9280, 256, 0, stream>>>(x16, wf1, b1, h1);
    // conv2: T=4 -> NG=3, NW=20736; CG=4 (dbuf 32KB, 6 chunks)
    //   regs ~ 64 + 56 + 45 = 165 -> 3 waves/SIMD
    conv4d_v11<3, 9, 4, 15, 16, 2, 12, 4, 4, 3><<<5184, 256, 0, stream>>>(h1, wf2, b2, h2);
    // conv3: T=3 -> NG=3, NW=9984; CG=6 (dbuf 48KB, 12 chunks, 3 blocks/CU)
    conv4d_v11<9, 12, 4, 12, 12, 2, 10, 3, 6, 3><<<2496, 256, 0, stream>>>(h2, wf3, b3, h3);
    // conv4: T=3 -> NG=2, NW=2048; CG=6 (16 chunks)
    conv4d_v11<12, 15, 4, 9, 10, 2, 6, 3, 6, 3><<<512, 256, 0, stream>>>(h3, wf4, b4, h4);
    // conv5: T=4, CG=6 (15 chunks, 36KB dbuf); NW=256
    conv4d_v11<15, 15, 3, 6, 6, 2, 4, 4, 6, 3><<<64, 256, 0, stream>>>(h4, wf5, b5, h5);

    fc1_mfma<<<28, 256, 0, stream>>>(h5, wfc, fc1b, fc1out);
    fc2_sigmoid<<<1, 256, 0, stream>>>(fc1out, fc2w, fc2b, out);
}